// Round 9
// baseline (286.209 us; speedup 1.0000x reference)
//
#include <hip/hip_runtime.h>

// LinearRTU: B=8 T=2048 D=1024 H=1024 R=128
// ws: agg float2[8][128][1024] @8MiB (8MiB, pristine aggregates — no longer mutated)
//     Vt bf16[2][1024][128] @16MiB (512KiB, granule-XOR-swizzled by h&15)
//     Ubfp bf16[16][256][64] @16.5MiB (512KiB)
//     u_ws bf16 tiles [512*8][2][32][128] @17MiB (64MiB, swizzled image)
// R9 = R6 (green, 271.9us) with ONE change: k3 deleted; k4 computes its entry
// carry in-thread via the exact k3 Horner recurrence over pristine agg (bit-identical).

using u16 = unsigned short;
using frag_ab = __attribute__((ext_vector_type(8))) short;   // 8 bf16
using frag_cd = __attribute__((ext_vector_type(4))) float;   // 4 fp32

__device__ __forceinline__ u16 f2bf(float f) {
    union { float f; unsigned u; } v; v.f = f;
    unsigned r = v.u + 0x7FFFu + ((v.u >> 16) & 1u);   // RNE
    return (u16)(r >> 16);
}
__device__ __forceinline__ float bf2f(u16 s) {
    union { unsigned u; float f; } v; v.u = ((unsigned)s) << 16;
    return v.f;
}
__device__ __forceinline__ frag_cd mfma16(frag_ab a, frag_ab b, frag_cd c) {
    return __builtin_amdgcn_mfma_f32_16x16x32_bf16(a, b, c, 0, 0, 0);
}
__device__ __forceinline__ void lambda_of(const float* nu_log, const float* theta_log,
                                          int h, float& g, float& ph, float& gam)
{
    float rr = expf(-expf(nu_log[h]));
    float th = expf(theta_log[h]);
    g = rr * cosf(th);
    ph = rr * sinf(th);
    gam = sqrtf(fmaxf(1.0f - rr * rr, 0.0f));
}

// ------------- K0: U1|U2 -> Ubfp [kt=16][n=256][64] ; V1/V2 -> Vt (granule-swizzled) -------------
__global__ __launch_bounds__(256) void k0_pack(
    const float* __restrict__ U1, const float* __restrict__ U2,
    const float* __restrict__ V1, const float* __restrict__ V2,
    u16* __restrict__ Ubfp, u16* __restrict__ Vt)
{
    int idx = blockIdx.x * 256 + threadIdx.x;    // grid 256 -> 65536 items
    if (idx < 32768) {
        int kg = idx & 127, n = idx >> 7;        // n 0..255, k = kg*8..kg*8+7
        const float* Us = (n < 128) ? U1 : U2;
        int col = n & 127;
        u16 tmp[8];
#pragma unroll
        for (int j = 0; j < 8; ++j)
            tmp[j] = f2bf(Us[(size_t)(kg * 8 + j) * 128 + col]);
        *(uint4*)&Ubfp[((size_t)(kg >> 3) * 256 + n) * 64 + (kg & 7) * 8] = *(uint4*)tmp;
    } else {
        int i2 = idx - 32768;
        int kg = i2 & 15, h = (i2 >> 4) & 1023, br = i2 >> 14;
        const float* Vs = br ? V2 : V1;
        u16 tmp[8];
#pragma unroll
        for (int j = 0; j < 8; ++j)
            tmp[j] = f2bf(Vs[(size_t)(kg * 8 + j) * 1024 + h]);
        *(uint4*)&Vt[((size_t)br * 1024 + h) * 128 + (kg ^ (h & 15)) * 8] = *(uint4*)tmp;
    }
}

// ------------- kB: fused (x@U)@V + chunk aggregates + u persist (verbatim R6) -------------
__global__ __launch_bounds__(256, 2) void kB_fused(
    const float* __restrict__ x, const u16* __restrict__ Ubfp, const u16* __restrict__ Vt,
    const float* __restrict__ nu_log, const float* __restrict__ theta_log,
    float2* __restrict__ agg, u16* __restrict__ u_ws)
{
    __shared__ __align__(16) u16 smem[24576];
    const int tid = threadIdx.x;
    const int t0 = blockIdx.x * 32;
    const int wave = tid >> 6, lane = tid & 63;
    const int lm = lane & 15, q = lane >> 4;
    char* smb = (char*)smem;

    // ---------------- stage 1: xu[32][256] = bf16(x @ [U1|U2]) ----------------
    const int rowA = tid >> 3, kcA = tid & 7;      // 32 rows x 8 chunks
    frag_cd acc1[2][4] = {};
    const float* xsrc = x + (size_t)(t0 + rowA) * 1024 + kcA * 8;
    const char* bsrc = (const char*)Ubfp;

    float4 pA0 = *(const float4*)xsrc;
    float4 pA1 = *(const float4*)(xsrc + 4);

    for (int kt = 0; kt < 16; ++kt) {
        {
            u16 ap[8] = { f2bf(pA0.x), f2bf(pA0.y), f2bf(pA0.z), f2bf(pA0.w),
                          f2bf(pA1.x), f2bf(pA1.y), f2bf(pA1.z), f2bf(pA1.w) };
            *(uint4*)&smem[16640 + (rowA >> 3) * 520 + (rowA & 7) * 64 + kcA * 8] = *(uint4*)ap;
        }
#pragma unroll
        for (int i = 0; i < 8; ++i) {
            int blk = wave * 8 + i;               // 32 blocks of 1024 B
            __builtin_amdgcn_global_load_lds(
                (const __attribute__((address_space(1))) void*)(bsrc + (size_t)kt * 32768 + blk * 1024 + lane * 16),
                (__attribute__((address_space(3))) void*)(smb + blk * 1040), 16, 0, 0);
        }
        __syncthreads();
        if (kt + 1 < 16) {                        // prefetch next A tile (overlaps MFMA)
            pA0 = *(const float4*)(xsrc + (kt + 1) * 64);
            pA1 = *(const float4*)(xsrc + (kt + 1) * 64 + 4);
        }
        frag_ab a[2], b[4];
#pragma unroll
        for (int ksub = 0; ksub < 2; ++ksub) {
#pragma unroll
            for (int m2 = 0; m2 < 2; ++m2) {
                int ra = m2 * 16 + lm;
                a[m2] = *(const frag_ab*)&smem[16640 + (ra >> 3) * 520 + (ra & 7) * 64 + ksub * 32 + q * 8];
            }
#pragma unroll
            for (int n4 = 0; n4 < 4; ++n4) {
                int nb = wave * 64 + n4 * 16 + lm;
                b[n4] = *(const frag_ab*)&smem[(nb >> 3) * 520 + (nb & 7) * 64 + ksub * 32 + q * 8];
            }
#pragma unroll
            for (int m2 = 0; m2 < 2; ++m2)
#pragma unroll
                for (int n4 = 0; n4 < 4; ++n4)
                    acc1[m2][n4] = mfma16(a[m2], b[n4], acc1[m2][n4]);
        }
        __syncthreads();
    }
    // epilogue: acc1 -> xu LDS [32][256], granule swz keeps branch half, XOR low4 by t
#pragma unroll
    for (int m2 = 0; m2 < 2; ++m2)
#pragma unroll
        for (int n4 = 0; n4 < 4; ++n4)
#pragma unroll
            for (int i = 0; i < 4; ++i) {
                int t = m2 * 16 + q * 4 + i;
                int col = wave * 64 + n4 * 16 + lm;
                int gcol = col >> 3;
                int swz = (gcol & 16) | ((gcol ^ t) & 15);
                smem[t * 256 + swz * 8 + (col & 7)] = f2bf(acc1[m2][n4][i]);
            }
    __syncthreads();

    // ---------------- stage 2: u = xu @ V per 128-h chunk ----------------
    const int hl = tid & 127, sc = tid >> 7;
    const int b = t0 >> 11;
    const int ncb = (t0 & 2047) >> 4;

    for (int c = 0; c < 8; ++c) {
        frag_cd acc2[2][2][2] = {};   // [br][m2][n2]
#pragma unroll
        for (int br = 0; br < 2; ++br) {
            const char* vsrc = (const char*)Vt + ((size_t)br * 1024 + c * 128) * 256;
#pragma unroll
            for (int i = 0; i < 8; ++i) {
                int blk = wave * 8 + i;           // 32 KB tile, linear
                __builtin_amdgcn_global_load_lds(
                    (const __attribute__((address_space(1))) void*)(vsrc + blk * 1024 + lane * 16),
                    (__attribute__((address_space(3))) void*)(smb + 16384 + blk * 1024 + lane * 16), 16, 0, 0);
            }
            __syncthreads();                      // drains DMA
#pragma unroll
            for (int ks = 0; ks < 4; ++ks) {
                int gk = br * 16 + ks * 4 + q;
                int ra0 = lm, ra1 = 16 + lm;
                frag_ab a0 = *(const frag_ab*)&smem[ra0 * 256 + ((gk & 16) | ((gk ^ ra0) & 15)) * 8];
                frag_ab a1 = *(const frag_ab*)&smem[ra1 * 256 + ((gk & 16) | ((gk ^ ra1) & 15)) * 8];
                int gv = ks * 4 + q;
                int nb0 = wave * 32 + lm, nb1 = nb0 + 16;
                frag_ab b0 = *(const frag_ab*)&smem[8192 + nb0 * 128 + ((gv ^ (nb0 & 15)) * 8)];
                frag_ab b1 = *(const frag_ab*)&smem[8192 + nb1 * 128 + ((gv ^ (nb1 & 15)) * 8)];
                acc2[br][0][0] = mfma16(a0, b0, acc2[br][0][0]);
                acc2[br][0][1] = mfma16(a0, b1, acc2[br][0][1]);
                acc2[br][1][0] = mfma16(a1, b0, acc2[br][1][0]);
                acc2[br][1][1] = mfma16(a1, b1, acc2[br][1][1]);
            }
            __syncthreads();                      // done reading this V tile
        }
        // dump u -> P2 [br][t 32][h 128], granule-XOR(t&15)
#pragma unroll
        for (int br = 0; br < 2; ++br)
#pragma unroll
            for (int m2 = 0; m2 < 2; ++m2)
#pragma unroll
                for (int n2 = 0; n2 < 2; ++n2)
#pragma unroll
                    for (int i = 0; i < 4; ++i) {
                        int t = m2 * 16 + q * 4 + i;
                        int hloc = wave * 32 + n2 * 16 + lm;
                        int sw = ((hloc >> 3) ^ (t & 15)) * 8 + (hloc & 7);
                        smem[8192 + br * 4096 + t * 128 + sw] = f2bf(acc2[br][m2][n2][i]);
                    }
        __syncthreads();
        // scan: thread = (hl 0..127, sc 0..1), 16 steps each
        {
            int h = c * 128 + hl;
            float g, ph, gam;
            lambda_of(nu_log, theta_log, h, g, ph, gam);
            float bx = 0.f, by = 0.f;
#pragma unroll
            for (int j = 0; j < 16; ++j) {
                int tt = sc * 16 + j;
                int sw = ((hl >> 3) ^ (tt & 15)) * 8 + (hl & 7);
                float u1 = bf2f(smem[8192 + tt * 128 + sw]);
                float u2 = bf2f(smem[8192 + 4096 + tt * 128 + sw]);
                float ex = gam * u1, ey = gam * u2;
                float nx = fmaf(g, bx, fmaf(-ph, by, ex));
                float ny = fmaf(ph, bx, fmaf(g, by, ey));
                bx = nx; by = ny;
            }
            agg[((size_t)b * 128 + ncb + sc) * 1024 + h] = make_float2(bx, by);
        }
        // persist the 16 KB u tile (swizzled image, linear copy)
        {
            size_t ub = ((size_t)blockIdx.x * 8 + c) * 8192;
#pragma unroll
            for (int i = 0; i < 4; ++i) {
                uint4 v = *(const uint4*)&smem[(size_t)8192 + (i * 256 + tid) * 8];
                *(uint4*)&u_ws[ub + (size_t)(i * 256 + tid) * 8] = v;
            }
        }
        __syncthreads();   // P free before next chunk's DMA
    }
}

// ---------------- K4: streaming apply + in-thread carry scan (k3 folded in) ----------------
// grid (8 h-chunks, 128 t-blocks of 128), 256 thr. Lane owns 4 consecutive h + one 16-t chunk.
// Entry carry computed via k3's exact Horner recurrence over pristine agg (bit-identical).
__global__ __launch_bounds__(256) void k4_apply(
    const u16* __restrict__ u_ws,
    const float* __restrict__ nu_log, const float* __restrict__ theta_log,
    const float2* __restrict__ agg, const float* __restrict__ hc1,
    const float* __restrict__ hc2, float* __restrict__ out)
{
    const int tid = threadIdx.x;
    const int c = blockIdx.x;           // 0..7 (128-h chunk)
    const int t0 = blockIdx.y * 128;    // grid.y = 128
    const int hg = tid & 31, ck = tid >> 5;    // h-group (4 h), chunk 0..7
    const int h = c * 128 + hg * 4;
    const int b = t0 >> 11;
    const int tloc = t0 & 2047;
    const int nc = (tloc >> 4) + ck;

    float g[4], ph[4], gam[4];
#pragma unroll
    for (int k = 0; k < 4; ++k) lambda_of(nu_log, theta_log, h + k, g[k], ph[k], gam[k]);

    // ---- entry carry: Horner over aggregates (identical order/ops to old k3) ----
    float ax[4], ay[4];
#pragma unroll
    for (int k = 0; k < 4; ++k) {
        float axx = g[k], ayy = ph[k];            // lambda^16
#pragma unroll
        for (int i = 0; i < 4; ++i) { float nx = axx * axx - ayy * ayy, ny = 2.f * axx * ayy; axx = nx; ayy = ny; }
        ax[k] = axx; ay[k] = ayy;
    }
    float4 h1 = *(const float4*)&hc1[(size_t)b * 1024 + h];
    float4 h2 = *(const float4*)&hc2[(size_t)b * 1024 + h];
    float cx[4] = { h1.x, h1.y, h1.z, h1.w };
    float cy[4] = { h2.x, h2.y, h2.z, h2.w };
    {
        const float2* ap = agg + (size_t)b * 128 * 1024 + h;
        for (int j = 0; j < nc; ++j) {
            float4 a01 = *(const float4*)ap;
            float4 a23 = *(const float4*)(ap + 2);
            float axv[4] = { a01.x, a01.z, a23.x, a23.z };
            float ayv[4] = { a01.y, a01.w, a23.y, a23.w };
#pragma unroll
            for (int k = 0; k < 4; ++k) {
                float nx = fmaf(ax[k], cx[k], fmaf(-ay[k], cy[k], axv[k]));
                float ny = fmaf(ay[k], cx[k], fmaf(ax[k], cy[k], ayv[k]));
                cx[k] = nx; cy[k] = ny;
            }
            ap += 1024;
        }
    }

    const int tb32 = (t0 >> 5) + (ck >> 1);          // global 32-t tile index
    const u16* ut = u_ws + ((size_t)tb32 * 8 + c) * 8192;
    const int gi = hg >> 1, off = (hg & 1) * 4;      // granule / within-granule for h..h+3
    float* yb = out + (size_t)b * (2048 * 2048);

#pragma unroll
    for (int j = 0; j < 16; ++j) {
        int tt = (ck & 1) * 16 + j;                  // t within 32-t tile
        int sw = ((gi ^ (tt & 15)) * 8) + off;
        uint2 r1 = *(const uint2*)&ut[tt * 128 + sw];          // u1 x4 (bf16)
        uint2 r2 = *(const uint2*)&ut[4096 + tt * 128 + sw];   // u2 x4
        u16 a1[4]; *(uint2*)a1 = r1;
        u16 a2[4]; *(uint2*)a2 = r2;
#pragma unroll
        for (int k = 0; k < 4; ++k) {
            float u1 = bf2f(a1[k]), u2 = bf2f(a2[k]);
            float ex = gam[k] * u1, ey = gam[k] * u2;
            float nx = fmaf(g[k], cx[k], fmaf(-ph[k], cy[k], ex));
            float ny = fmaf(ph[k], cx[k], fmaf(g[k], cy[k], ey));
            cx[k] = nx; cy[k] = ny;
        }
        int t = tloc + ck * 16 + j;
        *(float4*)&yb[(size_t)t * 2048 + h]        = make_float4(cx[0], cx[1], cx[2], cx[3]);
        *(float4*)&yb[(size_t)t * 2048 + 1024 + h] = make_float4(cy[0], cy[1], cy[2], cy[3]);
    }
    if (tloc + ck * 16 == 2032) {   // chunk ends at t=2047: finals
        *(float4*)&out[(size_t)33554432 + (size_t)b * 1024 + h] =
            make_float4(cx[0], cx[1], cx[2], cx[3]);
        *(float4*)&out[(size_t)33554432 + 8192 + (size_t)b * 1024 + h] =
            make_float4(cy[0], cy[1], cy[2], cy[3]);
    }
}

extern "C" void kernel_launch(void* const* d_in, const int* in_sizes, int n_in,
                              void* d_out, int out_size, void* d_ws, size_t ws_size,
                              hipStream_t stream) {
    const float* x         = (const float*)d_in[0];
    const float* nu_log    = (const float*)d_in[1];
    const float* theta_log = (const float*)d_in[2];
    const float* U1        = (const float*)d_in[3];
    const float* U2        = (const float*)d_in[4];
    const float* V1        = (const float*)d_in[5];
    const float* V2        = (const float*)d_in[6];
    const float* hc1       = (const float*)d_in[7];
    const float* hc2       = (const float*)d_in[8];

    float2* agg  = (float2*)((char*)d_ws + (size_t)8 * 1024 * 1024);
    u16*    Vt   = (u16*)((char*)d_ws + (size_t)16 * 1024 * 1024);
    u16*    Ubfp = (u16*)((char*)d_ws + (size_t)16 * 1024 * 1024 + 512 * 1024);
    u16*    u_ws = (u16*)((char*)d_ws + (size_t)17 * 1024 * 1024);   // 64 MiB

    k0_pack<<<256, 256, 0, stream>>>(U1, U2, V1, V2, Ubfp, Vt);
    kB_fused<<<512, 256, 0, stream>>>(x, Ubfp, Vt, nu_log, theta_log, agg, u_ws);
    k4_apply<<<dim3(8, 128), 256, 0, stream>>>(u_ws, nu_log, theta_log, agg, hc1, hc2,
                                               (float*)d_out);
}

// Round 10
// 271.222 us; speedup vs baseline: 1.0553x; 1.0553x over previous
//
#include <hip/hip_runtime.h>

// LinearRTU: B=8 T=2048 D=1024 H=1024 R=128
// ws: agg/carries float2[8][128][1024] @8MiB (8MiB)
//     Vt bf16[2][1024][128] @16MiB (512KiB, granule-XOR-swizzled by h&15)
//     Ubfp bf16[16][256][64] @16.5MiB (512KiB)
//     u_ws bf16 tiles [512*8][2][32][128] @17MiB (64MiB, swizzled image)
// R10 = exact revert to R6 (best measured: 271.9us).
// Neighborhood mapped: (256,3) occupancy +1.5us (R8); register-tail −barriers +6us (R7);
// k3 fold-in +14us (R9); coop-kernel carry exchange: fails in harness (R3-R5).

using u16 = unsigned short;
using frag_ab = __attribute__((ext_vector_type(8))) short;   // 8 bf16
using frag_cd = __attribute__((ext_vector_type(4))) float;   // 4 fp32

__device__ __forceinline__ u16 f2bf(float f) {
    union { float f; unsigned u; } v; v.f = f;
    unsigned r = v.u + 0x7FFFu + ((v.u >> 16) & 1u);   // RNE
    return (u16)(r >> 16);
}
__device__ __forceinline__ float bf2f(u16 s) {
    union { unsigned u; float f; } v; v.u = ((unsigned)s) << 16;
    return v.f;
}
__device__ __forceinline__ frag_cd mfma16(frag_ab a, frag_ab b, frag_cd c) {
    return __builtin_amdgcn_mfma_f32_16x16x32_bf16(a, b, c, 0, 0, 0);
}
__device__ __forceinline__ void lambda_of(const float* nu_log, const float* theta_log,
                                          int h, float& g, float& ph, float& gam)
{
    float rr = expf(-expf(nu_log[h]));
    float th = expf(theta_log[h]);
    g = rr * cosf(th);
    ph = rr * sinf(th);
    gam = sqrtf(fmaxf(1.0f - rr * rr, 0.0f));
}

// ------------- K0: U1|U2 -> Ubfp [kt=16][n=256][64] ; V1/V2 -> Vt (granule-swizzled) -------------
__global__ __launch_bounds__(256) void k0_pack(
    const float* __restrict__ U1, const float* __restrict__ U2,
    const float* __restrict__ V1, const float* __restrict__ V2,
    u16* __restrict__ Ubfp, u16* __restrict__ Vt)
{
    int idx = blockIdx.x * 256 + threadIdx.x;    // grid 256 -> 65536 items
    if (idx < 32768) {
        int kg = idx & 127, n = idx >> 7;        // n 0..255, k = kg*8..kg*8+7
        const float* Us = (n < 128) ? U1 : U2;
        int col = n & 127;
        u16 tmp[8];
#pragma unroll
        for (int j = 0; j < 8; ++j)
            tmp[j] = f2bf(Us[(size_t)(kg * 8 + j) * 128 + col]);
        *(uint4*)&Ubfp[((size_t)(kg >> 3) * 256 + n) * 64 + (kg & 7) * 8] = *(uint4*)tmp;
    } else {
        int i2 = idx - 32768;
        int kg = i2 & 15, h = (i2 >> 4) & 1023, br = i2 >> 14;
        const float* Vs = br ? V2 : V1;
        u16 tmp[8];
#pragma unroll
        for (int j = 0; j < 8; ++j)
            tmp[j] = f2bf(Vs[(size_t)(kg * 8 + j) * 1024 + h]);
        *(uint4*)&Vt[((size_t)br * 1024 + h) * 128 + (kg ^ (h & 15)) * 8] = *(uint4*)tmp;
    }
}

// ------------- kB: fused (x@U)@V + chunk aggregates + u persist -------------
__global__ __launch_bounds__(256, 2) void kB_fused(
    const float* __restrict__ x, const u16* __restrict__ Ubfp, const u16* __restrict__ Vt,
    const float* __restrict__ nu_log, const float* __restrict__ theta_log,
    float2* __restrict__ agg, u16* __restrict__ u_ws)
{
    __shared__ __align__(16) u16 smem[24576];
    const int tid = threadIdx.x;
    const int t0 = blockIdx.x * 32;
    const int wave = tid >> 6, lane = tid & 63;
    const int lm = lane & 15, q = lane >> 4;
    char* smb = (char*)smem;

    // ---------------- stage 1: xu[32][256] = bf16(x @ [U1|U2]) ----------------
    const int rowA = tid >> 3, kcA = tid & 7;      // 32 rows x 8 chunks
    frag_cd acc1[2][4] = {};
    const float* xsrc = x + (size_t)(t0 + rowA) * 1024 + kcA * 8;
    const char* bsrc = (const char*)Ubfp;

    float4 pA0 = *(const float4*)xsrc;
    float4 pA1 = *(const float4*)(xsrc + 4);

    for (int kt = 0; kt < 16; ++kt) {
        {
            u16 ap[8] = { f2bf(pA0.x), f2bf(pA0.y), f2bf(pA0.z), f2bf(pA0.w),
                          f2bf(pA1.x), f2bf(pA1.y), f2bf(pA1.z), f2bf(pA1.w) };
            *(uint4*)&smem[16640 + (rowA >> 3) * 520 + (rowA & 7) * 64 + kcA * 8] = *(uint4*)ap;
        }
#pragma unroll
        for (int i = 0; i < 8; ++i) {
            int blk = wave * 8 + i;               // 32 blocks of 1024 B
            __builtin_amdgcn_global_load_lds(
                (const __attribute__((address_space(1))) void*)(bsrc + (size_t)kt * 32768 + blk * 1024 + lane * 16),
                (__attribute__((address_space(3))) void*)(smb + blk * 1040), 16, 0, 0);
        }
        __syncthreads();
        if (kt + 1 < 16) {                        // prefetch next A tile (overlaps MFMA)
            pA0 = *(const float4*)(xsrc + (kt + 1) * 64);
            pA1 = *(const float4*)(xsrc + (kt + 1) * 64 + 4);
        }
        frag_ab a[2], b[4];
#pragma unroll
        for (int ksub = 0; ksub < 2; ++ksub) {
#pragma unroll
            for (int m2 = 0; m2 < 2; ++m2) {
                int ra = m2 * 16 + lm;
                a[m2] = *(const frag_ab*)&smem[16640 + (ra >> 3) * 520 + (ra & 7) * 64 + ksub * 32 + q * 8];
            }
#pragma unroll
            for (int n4 = 0; n4 < 4; ++n4) {
                int nb = wave * 64 + n4 * 16 + lm;
                b[n4] = *(const frag_ab*)&smem[(nb >> 3) * 520 + (nb & 7) * 64 + ksub * 32 + q * 8];
            }
#pragma unroll
            for (int m2 = 0; m2 < 2; ++m2)
#pragma unroll
                for (int n4 = 0; n4 < 4; ++n4)
                    acc1[m2][n4] = mfma16(a[m2], b[n4], acc1[m2][n4]);
        }
        __syncthreads();
    }
    // epilogue: acc1 -> xu LDS [32][256], granule swz keeps branch half, XOR low4 by t
#pragma unroll
    for (int m2 = 0; m2 < 2; ++m2)
#pragma unroll
        for (int n4 = 0; n4 < 4; ++n4)
#pragma unroll
            for (int i = 0; i < 4; ++i) {
                int t = m2 * 16 + q * 4 + i;
                int col = wave * 64 + n4 * 16 + lm;
                int gcol = col >> 3;
                int swz = (gcol & 16) | ((gcol ^ t) & 15);
                smem[t * 256 + swz * 8 + (col & 7)] = f2bf(acc1[m2][n4][i]);
            }
    __syncthreads();

    // ---------------- stage 2: u = xu @ V per 128-h chunk ----------------
    const int hl = tid & 127, sc = tid >> 7;
    const int b = t0 >> 11;
    const int ncb = (t0 & 2047) >> 4;

    for (int c = 0; c < 8; ++c) {
        frag_cd acc2[2][2][2] = {};   // [br][m2][n2]
#pragma unroll
        for (int br = 0; br < 2; ++br) {
            const char* vsrc = (const char*)Vt + ((size_t)br * 1024 + c * 128) * 256;
#pragma unroll
            for (int i = 0; i < 8; ++i) {
                int blk = wave * 8 + i;           // 32 KB tile, linear
                __builtin_amdgcn_global_load_lds(
                    (const __attribute__((address_space(1))) void*)(vsrc + blk * 1024 + lane * 16),
                    (__attribute__((address_space(3))) void*)(smb + 16384 + blk * 1024 + lane * 16), 16, 0, 0);
            }
            __syncthreads();                      // drains DMA
#pragma unroll
            for (int ks = 0; ks < 4; ++ks) {
                int gk = br * 16 + ks * 4 + q;
                int ra0 = lm, ra1 = 16 + lm;
                frag_ab a0 = *(const frag_ab*)&smem[ra0 * 256 + ((gk & 16) | ((gk ^ ra0) & 15)) * 8];
                frag_ab a1 = *(const frag_ab*)&smem[ra1 * 256 + ((gk & 16) | ((gk ^ ra1) & 15)) * 8];
                int gv = ks * 4 + q;
                int nb0 = wave * 32 + lm, nb1 = nb0 + 16;
                frag_ab b0 = *(const frag_ab*)&smem[8192 + nb0 * 128 + ((gv ^ (nb0 & 15)) * 8)];
                frag_ab b1 = *(const frag_ab*)&smem[8192 + nb1 * 128 + ((gv ^ (nb1 & 15)) * 8)];
                acc2[br][0][0] = mfma16(a0, b0, acc2[br][0][0]);
                acc2[br][0][1] = mfma16(a0, b1, acc2[br][0][1]);
                acc2[br][1][0] = mfma16(a1, b0, acc2[br][1][0]);
                acc2[br][1][1] = mfma16(a1, b1, acc2[br][1][1]);
            }
            __syncthreads();                      // done reading this V tile
        }
        // dump u -> P2 [br][t 32][h 128], granule-XOR(t&15)
#pragma unroll
        for (int br = 0; br < 2; ++br)
#pragma unroll
            for (int m2 = 0; m2 < 2; ++m2)
#pragma unroll
                for (int n2 = 0; n2 < 2; ++n2)
#pragma unroll
                    for (int i = 0; i < 4; ++i) {
                        int t = m2 * 16 + q * 4 + i;
                        int hloc = wave * 32 + n2 * 16 + lm;
                        int sw = ((hloc >> 3) ^ (t & 15)) * 8 + (hloc & 7);
                        smem[8192 + br * 4096 + t * 128 + sw] = f2bf(acc2[br][m2][n2][i]);
                    }
        __syncthreads();
        // scan: thread = (hl 0..127, sc 0..1), 16 steps each
        {
            int h = c * 128 + hl;
            float g, ph, gam;
            lambda_of(nu_log, theta_log, h, g, ph, gam);
            float bx = 0.f, by = 0.f;
#pragma unroll
            for (int j = 0; j < 16; ++j) {
                int tt = sc * 16 + j;
                int sw = ((hl >> 3) ^ (tt & 15)) * 8 + (hl & 7);
                float u1 = bf2f(smem[8192 + tt * 128 + sw]);
                float u2 = bf2f(smem[8192 + 4096 + tt * 128 + sw]);
                float ex = gam * u1, ey = gam * u2;
                float nx = fmaf(g, bx, fmaf(-ph, by, ex));
                float ny = fmaf(ph, bx, fmaf(g, by, ey));
                bx = nx; by = ny;
            }
            agg[((size_t)b * 128 + ncb + sc) * 1024 + h] = make_float2(bx, by);
        }
        // persist the 16 KB u tile (swizzled image, linear copy)
        {
            size_t ub = ((size_t)blockIdx.x * 8 + c) * 8192;
#pragma unroll
            for (int i = 0; i < 4; ++i) {
                uint4 v = *(const uint4*)&smem[(size_t)8192 + (i * 256 + tid) * 8];
                *(uint4*)&u_ws[ub + (size_t)(i * 256 + tid) * 8] = v;
            }
        }
        __syncthreads();   // P free before next chunk's DMA
    }
}

// ---------------- K3: scan the 128 chunk aggregates per (b,h); in-place -> carries ----------------
__global__ __launch_bounds__(64) void k3_scan(
    float2* __restrict__ agg_carry, const float* __restrict__ nu_log,
    const float* __restrict__ theta_log, const float* __restrict__ hc1,
    const float* __restrict__ hc2)
{
    const int idx = blockIdx.x * 64 + threadIdx.x;   // 128 blocks x 64 = 8192
    const int b = idx >> 10, h = idx & 1023;
    float g, ph, gam;
    lambda_of(nu_log, theta_log, h, g, ph, gam);
    float ax = g, ay = ph;                            // lambda^16
#pragma unroll
    for (int i = 0; i < 4; ++i) { float nx = ax * ax - ay * ay, ny = 2.f * ax * ay; ax = nx; ay = ny; }
    float cx = hc1[idx], cy = hc2[idx];
    float2* acp = agg_carry + (size_t)b * 128 * 1024 + h;
#pragma unroll 8
    for (int c = 0; c < 128; ++c) {
        float2 a = acp[(size_t)c * 1024];
        acp[(size_t)c * 1024] = make_float2(cx, cy);
        float nx = fmaf(ax, cx, fmaf(-ay, cy, a.x));
        float ny = fmaf(ay, cx, fmaf(ax, cy, a.y));
        cx = nx; cy = ny;
    }
}

// ---------------- K4: vectorized streaming — uint2 u-loads, float4 y-stores, no LDS ----------------
// grid (8 h-chunks, 128 t-blocks of 128), 256 thr. Lane owns 4 consecutive h + one 16-t chunk.
__global__ __launch_bounds__(256) void k4_apply(
    const u16* __restrict__ u_ws,
    const float* __restrict__ nu_log, const float* __restrict__ theta_log,
    const float2* __restrict__ carries, float* __restrict__ out)
{
    const int tid = threadIdx.x;
    const int c = blockIdx.x;           // 0..7 (128-h chunk)
    const int t0 = blockIdx.y * 128;    // grid.y = 128
    const int hg = tid & 31, ck = tid >> 5;    // h-group (4 h), chunk 0..7
    const int h = c * 128 + hg * 4;
    const int b = t0 >> 11;
    const int tloc = t0 & 2047;
    const int nc = (tloc >> 4) + ck;

    float g[4], ph[4], gam[4];
#pragma unroll
    for (int k = 0; k < 4; ++k) lambda_of(nu_log, theta_log, h + k, g[k], ph[k], gam[k]);

    const float2* cp = carries + ((size_t)b * 128 + nc) * 1024 + h;
    float4 cab = *(const float4*)cp;
    float4 ccd = *(const float4*)(cp + 2);
    float cx[4] = { cab.x, cab.z, ccd.x, ccd.z };
    float cy[4] = { cab.y, cab.w, ccd.y, ccd.w };

    const int tb32 = (t0 >> 5) + (ck >> 1);          // global 32-t tile index
    const u16* ut = u_ws + ((size_t)tb32 * 8 + c) * 8192;
    const int gi = hg >> 1, off = (hg & 1) * 4;      // granule / within-granule for h..h+3
    float* yb = out + (size_t)b * (2048 * 2048);

#pragma unroll
    for (int j = 0; j < 16; ++j) {
        int tt = (ck & 1) * 16 + j;                  // t within 32-t tile
        int sw = ((gi ^ (tt & 15)) * 8) + off;
        uint2 r1 = *(const uint2*)&ut[tt * 128 + sw];          // u1 x4 (bf16)
        uint2 r2 = *(const uint2*)&ut[4096 + tt * 128 + sw];   // u2 x4
        u16 a1[4]; *(uint2*)a1 = r1;
        u16 a2[4]; *(uint2*)a2 = r2;
#pragma unroll
        for (int k = 0; k < 4; ++k) {
            float u1 = bf2f(a1[k]), u2 = bf2f(a2[k]);
            float ex = gam[k] * u1, ey = gam[k] * u2;
            float nx = fmaf(g[k], cx[k], fmaf(-ph[k], cy[k], ex));
            float ny = fmaf(ph[k], cx[k], fmaf(g[k], cy[k], ey));
            cx[k] = nx; cy[k] = ny;
        }
        int t = tloc + ck * 16 + j;
        *(float4*)&yb[(size_t)t * 2048 + h]        = make_float4(cx[0], cx[1], cx[2], cx[3]);
        *(float4*)&yb[(size_t)t * 2048 + 1024 + h] = make_float4(cy[0], cy[1], cy[2], cy[3]);
    }
    if (tloc + ck * 16 == 2032) {   // chunk ends at t=2047: finals
        *(float4*)&out[(size_t)33554432 + (size_t)b * 1024 + h] =
            make_float4(cx[0], cx[1], cx[2], cx[3]);
        *(float4*)&out[(size_t)33554432 + 8192 + (size_t)b * 1024 + h] =
            make_float4(cy[0], cy[1], cy[2], cy[3]);
    }
}

extern "C" void kernel_launch(void* const* d_in, const int* in_sizes, int n_in,
                              void* d_out, int out_size, void* d_ws, size_t ws_size,
                              hipStream_t stream) {
    const float* x         = (const float*)d_in[0];
    const float* nu_log    = (const float*)d_in[1];
    const float* theta_log = (const float*)d_in[2];
    const float* U1        = (const float*)d_in[3];
    const float* U2        = (const float*)d_in[4];
    const float* V1        = (const float*)d_in[5];
    const float* V2        = (const float*)d_in[6];
    const float* hc1       = (const float*)d_in[7];
    const float* hc2       = (const float*)d_in[8];

    float2* agg  = (float2*)((char*)d_ws + (size_t)8 * 1024 * 1024);
    u16*    Vt   = (u16*)((char*)d_ws + (size_t)16 * 1024 * 1024);
    u16*    Ubfp = (u16*)((char*)d_ws + (size_t)16 * 1024 * 1024 + 512 * 1024);
    u16*    u_ws = (u16*)((char*)d_ws + (size_t)17 * 1024 * 1024);   // 64 MiB

    k0_pack<<<256, 256, 0, stream>>>(U1, U2, V1, V2, Ubfp, Vt);
    kB_fused<<<512, 256, 0, stream>>>(x, Ubfp, Vt, nu_log, theta_log, agg, u_ws);
    k3_scan<<<128, 64, 0, stream>>>(agg, nu_log, theta_log, hc1, hc2);
    k4_apply<<<dim3(8, 128), 256, 0, stream>>>(u_ws, nu_log, theta_log, agg, (float*)d_out);
}